// Round 8
// baseline (145.507 us; speedup 1.0000x reference)
//
#include <hip/hip_runtime.h>
#include <hip/hip_bf16.h>

#define DDIM 448
#define NSTEP 14            // 448 / 32

typedef __hip_bfloat16 bf16;
typedef __attribute__((ext_vector_type(8))) short short8;   // 8 bf16 = 16B (MFMA A/B frag)
typedef __attribute__((ext_vector_type(4))) float f32x4;    // MFMA C/D frag / float4

__device__ __forceinline__ short bf_bits(float f) {
    bf16 h = __float2bfloat16(f);
    return *reinterpret_cast<short*>(&h);
}

// async global->LDS DMA: per-lane 16B; LDS dst = wave-uniform base + lane*16
__device__ __forceinline__ void async16(const bf16* g, bf16* l) {
    __builtin_amdgcn_global_load_lds(
        (const __attribute__((address_space(1))) void*)g,
        (__attribute__((address_space(3))) void*)l, 16, 0, 0);
}

// ---------------------------------------------------------------------------
// Kernel 1: fused weight  E[i][d] = Wq*diagA + Wk*diagB + Wv*diagC,
//           Wc[i][o] = sum_d E[i][d] * Wo[d][o].
// Output layout (verified): Wt[s][o][k] = Wc[s*32+k][o] — the GEMM's exact
// LDS image; each K-step slab is 28 KB contiguous -> 1 KB linear DMAs.
// UNCHANGED.
// ---------------------------------------------------------------------------
__global__ __launch_bounds__(256) void prep_wc(
    const float* __restrict__ Wq, const float* __restrict__ Wk,
    const float* __restrict__ Wv, const float* __restrict__ Wo,
    const float* __restrict__ Ad, const float* __restrict__ Bd,
    const float* __restrict__ Cd, bf16* __restrict__ Wt)
{
    __shared__ __align__(16) bf16 As[64 * 32];
    __shared__ __align__(16) bf16 Bs[64 * 32];
    __shared__ float da[DDIM], db[DDIM], dc[DDIM];

    const int tid  = threadIdx.x;
    const int i0   = blockIdx.x * 64;
    const int o0   = blockIdx.y * 64;
    const int lane = tid & 63;
    const int wid  = tid >> 6;
    const int wm   = wid >> 1, wn = wid & 1;
    const int m_   = lane & 15, kq = lane >> 4;

    for (int d = tid; d < DDIM; d += 256) {
        da[d] = Ad[d * DDIM + d];
        db[d] = Bd[d * DDIM + d];
        dc[d] = Cd[d * DDIM + d];
    }

    const int dr  = tid >> 3;
    const int oc8 = (tid & 7) * 8;
    const int ir  = tid >> 2;
    const int dc8 = (tid & 3) * 8;

    f32x4 acc[2][2] = {};

    f32x4 w0 = *(const f32x4*)(Wo + dr * DDIM + o0 + oc8);
    f32x4 w1 = *(const f32x4*)(Wo + dr * DDIM + o0 + oc8 + 4);
    f32x4 q0 = *(const f32x4*)(Wq + (i0 + ir) * DDIM + dc8);
    f32x4 q1 = *(const f32x4*)(Wq + (i0 + ir) * DDIM + dc8 + 4);
    f32x4 t0 = *(const f32x4*)(Wk + (i0 + ir) * DDIM + dc8);
    f32x4 t1 = *(const f32x4*)(Wk + (i0 + ir) * DDIM + dc8 + 4);
    f32x4 v0 = *(const f32x4*)(Wv + (i0 + ir) * DDIM + dc8);
    f32x4 v1 = *(const f32x4*)(Wv + (i0 + ir) * DDIM + dc8 + 4);

    for (int k0 = 0; k0 < DDIM; k0 += 32) {
        __syncthreads();
        #pragma unroll
        for (int j = 0; j < 4; ++j) {
            As[(oc8 + j) * 32 + dr]     = __float2bfloat16(w0[j]);
            As[(oc8 + 4 + j) * 32 + dr] = __float2bfloat16(w1[j]);
        }
        short8 e;
        #pragma unroll
        for (int j = 0; j < 4; ++j) {
            e[j]     = bf_bits(q0[j] * da[k0 + dc8 + j]
                             + t0[j] * db[k0 + dc8 + j]
                             + v0[j] * dc[k0 + dc8 + j]);
            e[j + 4] = bf_bits(q1[j] * da[k0 + dc8 + 4 + j]
                             + t1[j] * db[k0 + dc8 + 4 + j]
                             + v1[j] * dc[k0 + dc8 + 4 + j]);
        }
        *(short8*)&Bs[ir * 32 + dc8] = e;
        __syncthreads();

        const int kn = (k0 + 32 < DDIM) ? k0 + 32 : 0;
        w0 = *(const f32x4*)(Wo + (kn + dr) * DDIM + o0 + oc8);
        w1 = *(const f32x4*)(Wo + (kn + dr) * DDIM + o0 + oc8 + 4);
        q0 = *(const f32x4*)(Wq + (i0 + ir) * DDIM + kn + dc8);
        q1 = *(const f32x4*)(Wq + (i0 + ir) * DDIM + kn + dc8 + 4);
        t0 = *(const f32x4*)(Wk + (i0 + ir) * DDIM + kn + dc8);
        t1 = *(const f32x4*)(Wk + (i0 + ir) * DDIM + kn + dc8 + 4);
        v0 = *(const f32x4*)(Wv + (i0 + ir) * DDIM + kn + dc8);
        v1 = *(const f32x4*)(Wv + (i0 + ir) * DDIM + kn + dc8 + 4);

        short8 af[2], bfr[2];
        #pragma unroll
        for (int mi = 0; mi < 2; ++mi)
            af[mi] = *(const short8*)&As[(wm * 32 + mi * 16 + m_) * 32 + kq * 8];
        #pragma unroll
        for (int ni = 0; ni < 2; ++ni)
            bfr[ni] = *(const short8*)&Bs[(wn * 32 + ni * 16 + m_) * 32 + kq * 8];
        #pragma unroll
        for (int mi = 0; mi < 2; ++mi)
            #pragma unroll
            for (int ni = 0; ni < 2; ++ni)
                acc[mi][ni] = __builtin_amdgcn_mfma_f32_16x16x32_bf16(
                    af[mi], bfr[ni], acc[mi][ni], 0, 0, 0);
    }

    #pragma unroll
    for (int mi = 0; mi < 2; ++mi)
        #pragma unroll
        for (int ni = 0; ni < 2; ++ni) {
            const int o = o0 + wm * 32 + mi * 16 + kq * 4;
            const int i = i0 + wn * 32 + ni * 16 + m_;
            bf16* dst = Wt + (i >> 5) * (DDIM * 32) + (i & 31);
            #pragma unroll
            for (int r = 0; r < 4; ++r)
                dst[(o + r) * 32] = __float2bfloat16(acc[mi][ni][r]);
        }
}

// ---------------------------------------------------------------------------
// Kernel 2: out[M x 448](fp32) = X(fp32) @ Wc.  B supplied as Wt[s][o][k].
// v8: READ/WRITE OVERLAP via 2 blocks/CU. Arithmetic: per CU the X-read
// phase (~9.5 µs) and the C-write phase (~9.5 µs) were SERIAL in v1-v7
// (single block/CU: epilogue starts only when the K-loop ends), so the
// read pipe idles during stores and vice versa — matching v6's ~33 µs vs
// the ~19 µs serial floor. Two co-resident blocks stagger: one block's
// lgkm-only epilogue stores drain under the other's main loop.
// Geometry: BM=64, 256 thr / 4 waves, acc[4][7] (~180 VGPR <= 256 ->
// 2 waves/SIMD with both blocks), LDS 64 KB/block -> exactly 2 blocks/CU,
// grid 512. Kept from the ladder: linear 1 KB B-DMA (R3), counted vmcnt +
// raw barriers (R6), lgkm-only epilogue (R7-verified).
// Pipeline (B double-buffered): DMA B(s+1) issued at TOP of step s, waited
// at END of step s -> ~full step of slack; end-of-step wait is vmcnt(2)
// (retires B(s+1); keeps the 2 X(s+2) loads in flight across the barrier).
// Counts are uniform: ALL 4 waves issue 7 DMAs + 2 X loads; no stores are
// ever outstanding inside the loop (epilogue stores start after it).
// smem: A0 @0 (4K), A1 @4K, B0 @8K (28K), B1 @36K (28K) = 64 KB.
// Epilogue Cb @8K: 16 x 452 x 4B = 28.9 KB (aliases B0+256B of B1; both
// dead by then). 4 stages of 16 rows, stride-452 (2-way conflict = free).
// ---------------------------------------------------------------------------
__global__ __launch_bounds__(256, 2) void gemm_xwc(
    const float* __restrict__ X, const bf16* __restrict__ Wt,
    float* __restrict__ out)
{
    __shared__ __align__(16) char smem[65536];          // 64 KB

    const int tid  = threadIdx.x;
    const int lane = tid & 63;
    const int wid  = tid >> 6;               // col quarter: 112 cols
    const int m_   = lane & 15;
    const int kq   = lane >> 4;
    const int row0 = blockIdx.x * 64;

    // A staging: 64x32 fp32 -> 8 f32/thread
    const int ar = tid >> 2;                 // 0..63
    const int ac = (tid & 3) * 8;            // 0,8,16,24
    const float* agp = X + (row0 + ar) * DDIM + ac;

    // B DMA: instr j moves 1 KB linear from the Wt K-step slab
    const bf16* bgp = Wt + wid * 7 * 512 + lane * 8;

    f32x4 acc[4][7] = {};

    // ---- prologue -------------------------------------------------------
    // issue order: X(0) | stage A(0) (compiler waits X(0), keeps B/X order)
    //              | DMA B(0) | X(1)
    // end wait vmcnt(2): retires B(0) (older), keeps X(1) in flight.
    f32x4 a0 = *(const f32x4*)(agp);
    f32x4 a1 = *(const f32x4*)(agp + 4);
    {
        bf16* A0 = (bf16*)smem;
        short8 w;
        #pragma unroll
        for (int j = 0; j < 4; ++j) {
            w[j] = bf_bits(a0[j]); w[j + 4] = bf_bits(a1[j]);
        }
        *(short8*)&A0[ar * 32 + ac] = w;     // byte addr = tid*16
    }
    {
        bf16* B0 = (bf16*)(smem + 8192);
        #pragma unroll
        for (int j = 0; j < 7; ++j)
            async16(bgp + j * 512, B0 + (wid * 7 + j) * 512);
    }
    a0 = *(const f32x4*)(agp + 32);          // X(1)
    a1 = *(const f32x4*)(agp + 36);
    asm volatile("s_waitcnt vmcnt(2)" ::: "memory");
    asm volatile("s_waitcnt lgkmcnt(0)" ::: "memory");
    __builtin_amdgcn_s_barrier();            // A(0)+B(0) ready; X(1) in flight

    for (int s = 0; s < NSTEP; ++s) {
        const bf16* Ac = (const bf16*)(smem + ((s & 1) << 12));          // 0/4K
        const bf16* Bc = (const bf16*)(smem + 8192 + (s & 1) * 28672);   // 8K/36K

        // 1. DMA B(s+1) into the freed buffer (read last step, fenced by
        //    the barrier we just crossed)
        if (s + 1 < NSTEP) {                  // uniform
            bf16* Bn = (bf16*)(smem + 8192 + ((s + 1) & 1) * 28672);
            const bf16* bsrc = bgp + (s + 1) * (DDIM * 32);
            #pragma unroll
            for (int j = 0; j < 7; ++j)
                async16(bsrc + j * 512, Bn + (wid * 7 + j) * 512);
            // 2. stage A(s+1) from a-regs (hold X(s+1))
            bf16* An = (bf16*)(smem + (((s + 1) & 1) << 12));
            short8 w;
            #pragma unroll
            for (int j = 0; j < 4; ++j) {
                w[j] = bf_bits(a0[j]); w[j + 4] = bf_bits(a1[j]);
            }
            *(short8*)&An[ar * 32 + ac] = w;
        }
        // 3. load X(s+2) a-regs
        if (s + 2 < NSTEP) {                  // uniform
            const int k2 = (s + 2) * 32;
            a0 = *(const f32x4*)(agp + k2);
            a1 = *(const f32x4*)(agp + k2 + 4);
        }

        // 4. fragments + MFMA on (A(s), B(s))
        short8 af[4], bfr[7];
        #pragma unroll
        for (int mi = 0; mi < 4; ++mi)
            af[mi] = *(const short8*)&Ac[(mi * 16 + m_) * 32 + kq * 8];
        #pragma unroll
        for (int ni = 0; ni < 7; ++ni)
            bfr[ni] = *(const short8*)&Bc[(wid * 112 + ni * 16 + m_) * 32 + kq * 8];

        #pragma unroll
        for (int mi = 0; mi < 4; ++mi)
            #pragma unroll
            for (int ni = 0; ni < 7; ++ni)
                acc[mi][ni] = __builtin_amdgcn_mfma_f32_16x16x32_bf16(
                    af[mi], bfr[ni], acc[mi][ni], 0, 0, 0);

        // 5. counted wait: retire B(s+1) (issued at top of THIS step, ~full
        //    step of slack); keep X(s+2) (2 newest) in flight.
        if (s + 2 < NSTEP) {
            asm volatile("s_waitcnt vmcnt(2)" ::: "memory");
        } else {
            asm volatile("s_waitcnt vmcnt(0)" ::: "memory");
        }
        asm volatile("s_waitcnt lgkmcnt(0)" ::: "memory");
        __builtin_amdgcn_s_barrier();
    }

    // ---- epilogue: 4 stages of 16 rows; padded LDS bounce (stride 452 f32)
    // lgkm-only barriers (v7-verified): stores drain in the background —
    // overlapped by the co-resident block's main loop.
    float* Cb = (float*)(smem + 8192);        // 16 x 452 fp32 = 28.9 KB
    const int erow = tid >> 4;                // 0..15
    const int ec0  = tid & 15;
    #pragma unroll
    for (int t = 0; t < 4; ++t) {
        #pragma unroll
        for (int ni = 0; ni < 7; ++ni) {
            const int col = wid * 112 + ni * 16 + m_;
            #pragma unroll
            for (int r = 0; r < 4; ++r)
                Cb[(kq * 4 + r) * 452 + col] = acc[t][ni][r];
        }
        asm volatile("s_waitcnt lgkmcnt(0)" ::: "memory");
        __builtin_amdgcn_s_barrier();         // Cb writes visible
        float* dst = out + (row0 + t * 16) * DDIM;
        #pragma unroll
        for (int j = 0; j < 7; ++j)
            *(f32x4*)(dst + erow * DDIM + (ec0 + j * 16) * 4) =
                *(const f32x4*)(Cb + erow * 452 + (ec0 + j * 16) * 4);
        asm volatile("s_waitcnt lgkmcnt(0)" ::: "memory");
        __builtin_amdgcn_s_barrier();         // Cb reads done; safe to overwrite
    }
}

// ---------------------------------------------------------------------------
extern "C" void kernel_launch(void* const* d_in, const int* in_sizes, int n_in,
                              void* d_out, int out_size, void* d_ws, size_t ws_size,
                              hipStream_t stream) {
    const float* x  = (const float*)d_in[0];
    const float* Wq = (const float*)d_in[1];
    const float* Wk = (const float*)d_in[2];
    const float* Wv = (const float*)d_in[3];
    const float* Wo = (const float*)d_in[4];
    const float* Ad = (const float*)d_in[5];
    const float* Bd = (const float*)d_in[6];
    const float* Cd = (const float*)d_in[7];

    bf16*  Wt  = (bf16*)d_ws;                      // 448*448*2 = 392 KiB scratch
    float* out = (float*)d_out;

    const int M = in_sizes[0] / DDIM;              // 32768

    prep_wc<<<dim3(7, 7), 256, 0, stream>>>(Wq, Wk, Wv, Wo, Ad, Bd, Cd, Wt);
    gemm_xwc<<<M / 64, 256, 0, stream>>>(x, Wt, out);
}

// Round 9
// 140.103 us; speedup vs baseline: 1.0386x; 1.0386x over previous
//
#include <hip/hip_runtime.h>
#include <hip/hip_bf16.h>

#define DDIM 448
#define NSTEP 14            // 448 / 32

typedef __hip_bfloat16 bf16;
typedef __attribute__((ext_vector_type(8))) short short8;   // 8 bf16 = 16B (MFMA A/B frag)
typedef __attribute__((ext_vector_type(4))) float f32x4;    // MFMA C/D frag / float4

__device__ __forceinline__ short bf_bits(float f) {
    bf16 h = __float2bfloat16(f);
    return *reinterpret_cast<short*>(&h);
}

// async global->LDS DMA: per-lane 16B; LDS dst = wave-uniform base + lane*16
__device__ __forceinline__ void async16(const bf16* g, bf16* l) {
    __builtin_amdgcn_global_load_lds(
        (const __attribute__((address_space(1))) void*)g,
        (__attribute__((address_space(3))) void*)l, 16, 0, 0);
}

// ---------------------------------------------------------------------------
// Kernel 1: fused weight  E[i][d] = Wq*diagA + Wk*diagB + Wv*diagC,
//           Wc[i][o] = sum_d E[i][d] * Wo[d][o].
// Output layout (verified): Wt[s][o][k] = Wc[s*32+k][o] — 28 KB contiguous
// per K-step slab -> 1 KB linear DMAs.  UNCHANGED.
// ---------------------------------------------------------------------------
__global__ __launch_bounds__(256) void prep_wc(
    const float* __restrict__ Wq, const float* __restrict__ Wk,
    const float* __restrict__ Wv, const float* __restrict__ Wo,
    const float* __restrict__ Ad, const float* __restrict__ Bd,
    const float* __restrict__ Cd, bf16* __restrict__ Wt)
{
    __shared__ __align__(16) bf16 As[64 * 32];
    __shared__ __align__(16) bf16 Bs[64 * 32];
    __shared__ float da[DDIM], db[DDIM], dc[DDIM];

    const int tid  = threadIdx.x;
    const int i0   = blockIdx.x * 64;
    const int o0   = blockIdx.y * 64;
    const int lane = tid & 63;
    const int wid  = tid >> 6;
    const int wm   = wid >> 1, wn = wid & 1;
    const int m_   = lane & 15, kq = lane >> 4;

    for (int d = tid; d < DDIM; d += 256) {
        da[d] = Ad[d * DDIM + d];
        db[d] = Bd[d * DDIM + d];
        dc[d] = Cd[d * DDIM + d];
    }

    const int dr  = tid >> 3;
    const int oc8 = (tid & 7) * 8;
    const int ir  = tid >> 2;
    const int dc8 = (tid & 3) * 8;

    f32x4 acc[2][2] = {};

    f32x4 w0 = *(const f32x4*)(Wo + dr * DDIM + o0 + oc8);
    f32x4 w1 = *(const f32x4*)(Wo + dr * DDIM + o0 + oc8 + 4);
    f32x4 q0 = *(const f32x4*)(Wq + (i0 + ir) * DDIM + dc8);
    f32x4 q1 = *(const f32x4*)(Wq + (i0 + ir) * DDIM + dc8 + 4);
    f32x4 t0 = *(const f32x4*)(Wk + (i0 + ir) * DDIM + dc8);
    f32x4 t1 = *(const f32x4*)(Wk + (i0 + ir) * DDIM + dc8 + 4);
    f32x4 v0 = *(const f32x4*)(Wv + (i0 + ir) * DDIM + dc8);
    f32x4 v1 = *(const f32x4*)(Wv + (i0 + ir) * DDIM + dc8 + 4);

    for (int k0 = 0; k0 < DDIM; k0 += 32) {
        __syncthreads();
        #pragma unroll
        for (int j = 0; j < 4; ++j) {
            As[(oc8 + j) * 32 + dr]     = __float2bfloat16(w0[j]);
            As[(oc8 + 4 + j) * 32 + dr] = __float2bfloat16(w1[j]);
        }
        short8 e;
        #pragma unroll
        for (int j = 0; j < 4; ++j) {
            e[j]     = bf_bits(q0[j] * da[k0 + dc8 + j]
                             + t0[j] * db[k0 + dc8 + j]
                             + v0[j] * dc[k0 + dc8 + j]);
            e[j + 4] = bf_bits(q1[j] * da[k0 + dc8 + 4 + j]
                             + t1[j] * db[k0 + dc8 + 4 + j]
                             + v1[j] * dc[k0 + dc8 + 4 + j]);
        }
        *(short8*)&Bs[ir * 32 + dc8] = e;
        __syncthreads();

        const int kn = (k0 + 32 < DDIM) ? k0 + 32 : 0;
        w0 = *(const f32x4*)(Wo + (kn + dr) * DDIM + o0 + oc8);
        w1 = *(const f32x4*)(Wo + (kn + dr) * DDIM + o0 + oc8 + 4);
        q0 = *(const f32x4*)(Wq + (i0 + ir) * DDIM + kn + dc8);
        q1 = *(const f32x4*)(Wq + (i0 + ir) * DDIM + kn + dc8 + 4);
        t0 = *(const f32x4*)(Wk + (i0 + ir) * DDIM + kn + dc8);
        t1 = *(const f32x4*)(Wk + (i0 + ir) * DDIM + kn + dc8 + 4);
        v0 = *(const f32x4*)(Wv + (i0 + ir) * DDIM + kn + dc8);
        v1 = *(const f32x4*)(Wv + (i0 + ir) * DDIM + kn + dc8 + 4);

        short8 af[2], bfr[2];
        #pragma unroll
        for (int mi = 0; mi < 2; ++mi)
            af[mi] = *(const short8*)&As[(wm * 32 + mi * 16 + m_) * 32 + kq * 8];
        #pragma unroll
        for (int ni = 0; ni < 2; ++ni)
            bfr[ni] = *(const short8*)&Bs[(wn * 32 + ni * 16 + m_) * 32 + kq * 8];
        #pragma unroll
        for (int mi = 0; mi < 2; ++mi)
            #pragma unroll
            for (int ni = 0; ni < 2; ++ni)
                acc[mi][ni] = __builtin_amdgcn_mfma_f32_16x16x32_bf16(
                    af[mi], bfr[ni], acc[mi][ni], 0, 0, 0);
    }

    #pragma unroll
    for (int mi = 0; mi < 2; ++mi)
        #pragma unroll
        for (int ni = 0; ni < 2; ++ni) {
            const int o = o0 + wm * 32 + mi * 16 + kq * 4;
            const int i = i0 + wn * 32 + ni * 16 + m_;
            bf16* dst = Wt + (i >> 5) * (DDIM * 32) + (i & 31);
            #pragma unroll
            for (int r = 0; r < 4; ++r)
                dst[(o + r) * 32] = __float2bfloat16(acc[mi][ni][r]);
        }
}

// ---------------------------------------------------------------------------
// Kernel 2: out[M x 448](fp32) = X(fp32) @ Wc.  B supplied as Wt[s][o][k].
// v9 = v6 (best: 128x448 tile, 512 thr / 8 waves, B triple-buffered linear
// DMA, counted vmcnt(9) + raw barriers) + two evidence-backed fixes:
//  1. T2 XOR-SWIZZLE on the LDS tiles. Both A and B are [row][32]bf16 =
//     64B rows; frag reads (16 lanes, rows m_=0..15, fixed 16B chunk kq)
//     hit bank (row*16+kq*4)%32 -> 8-WAY CONFLICT (the measured 1.5-1.7M
//     SQ_LDS_BANK_CONFLICT; ~5.4 extra cy per b128). Swizzle
//     SWZ(x) = x ^ (((x>>7)&7)<<4): control bits 7-9 (row>>1) disjoint
//     from modified bits 4-6 -> involution, confined to 1KB. Result: all
//     frag reads AND the A-stage ds_write go 8-way -> 2-way (free, m136).
//     B keeps a LINEAR DMA dest (rule #21) with the per-lane GLOBAL
//     source pre-swizzled: lane*16 ^ ((lane>>3 &7)<<4); j*1024 and slab
//     offsets sit above bit 9 -> swizzle-neutral. A (reg-staged) is
//     swizzled directly on the ds_write side.
//  2. DIRECT C-STORES: epilogue LDS bounce removed. 112 scalar f32
//     stores/thread; each wave-instr writes 4x64B fully-dirty sectors
//     (L2 write-combines; HBM write traffic unchanged). Removes 112 LDS
//     writes + 28 LDS reads + 8 barriers + all epilogue waits; stores
//     drain at endpgm (v7-verified semantics).
// smem: A0 @0 (8K), A1 @8K, B @16K/44K/72K (3x28K) = 100 KB, 1 block/CU.
// ---------------------------------------------------------------------------
__global__ __launch_bounds__(512, 2) void gemm_xwc(
    const float* __restrict__ X, const bf16* __restrict__ Wt,
    float* __restrict__ out)
{
    __shared__ __align__(16) char smem[102400];         // 100 KB

    const int tid  = threadIdx.x;
    const int lane = tid & 63;
    const int wid  = tid >> 6;               // 0..7
    const int wr   = wid >> 2;               // row half: rows wr*64 + [0,64)
    const int wc   = wid & 3;                // col quarter: cols wc*112 + [0,112)
    const int m_   = lane & 15;
    const int kq   = lane >> 4;
    const int row0 = blockIdx.x * 128;

    // A staging: 128x32 fp32 -> 8 f32/thread
    const int ar  = tid >> 2;                // 0..127
    const int ac4 = tid & 3;                 // 16B chunk index 0..3
    const float* agp = X + (row0 + ar) * DDIM + ac4 * 8;

    // ---- swizzle constants (SWZ(x) = x ^ (((x>>7)&7)<<4), bytes) ----
    // B DMA source: per-lane pre-swizzled global offset (dest stays linear)
    const int lsw = (lane * 16) ^ (((lane >> 3) & 7) << 4);
    const bf16* bgp = Wt + wc * 7 * 512 + (lsw >> 1);
    // frag-read offset (same per-lane pattern for A and B tiles)
    const int fb  = m_ * 64 + kq * 16;
    const int fsw = fb ^ (((fb >> 7) & 7) << 4);
    // A-stage write offset
    const int ab  = ar * 64 + ac4 * 16;
    const int asw = ab ^ (((ab >> 7) & 7) << 4);

    f32x4 acc[4][7] = {};

    // ---- prologue -------------------------------------------------------
    // issue order: X(0) | stage A(0) | X(1) | DMA B(0) | DMA B(1)
    // wait vmcnt(7): B(0) is within the 9 oldest of <=16 -> retired;
    // B(1)/X(1) stay in flight. Waves 4-7 hold <=2 -> no-op wait.
    f32x4 a0 = *(const f32x4*)(agp);
    f32x4 a1 = *(const f32x4*)(agp + 4);
    {
        short8 w;
        #pragma unroll
        for (int j = 0; j < 4; ++j) {
            w[j] = bf_bits(a0[j]); w[j + 4] = bf_bits(a1[j]);
        }
        *(short8*)(smem + asw) = w;          // A(0), swizzled
    }
    a0 = *(const f32x4*)(agp + 32);          // X(1)
    a1 = *(const f32x4*)(agp + 36);
    if (wid < 4) {
        bf16* B0 = (bf16*)(smem + 16384);
        bf16* B1 = (bf16*)(smem + 16384 + 28672);
        #pragma unroll
        for (int j = 0; j < 7; ++j)
            async16(bgp + j * 512, B0 + (wc * 7 + j) * 512);
        const bf16* b1 = bgp + DDIM * 32;
        #pragma unroll
        for (int j = 0; j < 7; ++j)
            async16(b1 + j * 512, B1 + (wc * 7 + j) * 512);
    }
    asm volatile("s_waitcnt vmcnt(7)" ::: "memory");
    asm volatile("s_waitcnt lgkmcnt(0)" ::: "memory");
    __builtin_amdgcn_s_barrier();            // A(0)+B(0) ready; B(1) in flight

    int bcur = 0;                            // buf idx of B(s)
    int bn2  = 2;                            // buf idx of B(s+2)
    for (int s = 0; s < NSTEP; ++s) {
        const char* AcB = (const char*)smem + ((s & 1) << 13) + wr * 4096;
        const char* BcB = (const char*)smem + 16384 + bcur * 28672 + wc * 7168;

        // 1. stage A(s+1) from a-regs (loaded last step / prologue)
        if (s + 1 < NSTEP) {                  // uniform
            char* An = (char*)smem + (((s + 1) & 1) << 13);
            short8 w;
            #pragma unroll
            for (int j = 0; j < 4; ++j) {
                w[j] = bf_bits(a0[j]); w[j + 4] = bf_bits(a1[j]);
            }
            *(short8*)(An + asw) = w;         // swizzled
        }
        // 2. load X(s+2) a-regs
        if (s + 2 < NSTEP) {                  // uniform
            const int k2 = (s + 2) * 32;
            a0 = *(const f32x4*)(agp + k2);
            a1 = *(const f32x4*)(agp + k2 + 4);
        }
        // 3. DMA B(s+2) into buf (s+2)%3 (linear dest, swizzled source)
        if (s + 2 < NSTEP && wid < 4) {       // wave-uniform
            bf16* Bn = (bf16*)(smem + 16384 + bn2 * 28672);
            const bf16* bsrc = bgp + (s + 2) * (DDIM * 32);
            #pragma unroll
            for (int j = 0; j < 7; ++j)
                async16(bsrc + j * 512, Bn + (wc * 7 + j) * 512);
        }

        // 4. fragments (swizzled reads) + MFMA on (A(s), B(s))
        short8 af[4], bfr[7];
        #pragma unroll
        for (int mi = 0; mi < 4; ++mi)
            af[mi] = *(const short8*)(AcB + mi * 1024 + fsw);
        #pragma unroll
        for (int ni = 0; ni < 7; ++ni)
            bfr[ni] = *(const short8*)(BcB + ni * 1024 + fsw);

        #pragma unroll
        for (int mi = 0; mi < 4; ++mi)
            #pragma unroll
            for (int ni = 0; ni < 7; ++ni)
                acc[mi][ni] = __builtin_amdgcn_mfma_f32_16x16x32_bf16(
                    af[mi], bfr[ni], acc[mi][ni], 0, 0, 0);

        // 5. counted wait: retire B(s+1) only; keep X(s+2)+B(s+2) in flight
        if (s < NSTEP - 2) {
            asm volatile("s_waitcnt vmcnt(9)" ::: "memory");
        } else {
            asm volatile("s_waitcnt vmcnt(0)" ::: "memory");
        }
        asm volatile("s_waitcnt lgkmcnt(0)" ::: "memory");
        __builtin_amdgcn_s_barrier();

        bcur = (bcur == 2) ? 0 : bcur + 1;
        bn2  = (bn2  == 2) ? 0 : bn2  + 1;
    }

    // ---- epilogue: direct scalar stores, no LDS bounce, no barriers.
    // Each wave-instr writes 4 rows x 16 consecutive f32 = 4x64B dirty
    // sectors; L2 write-combines to full lines (block covers all 448 cols).
    {
        const int crow = row0 + wr * 64 + kq * 4;
        const int ccol = wc * 112 + m_;
        #pragma unroll
        for (int mi = 0; mi < 4; ++mi)
            #pragma unroll
            for (int ni = 0; ni < 7; ++ni) {
                float* dst = out + (crow + mi * 16) * DDIM + ccol + ni * 16;
                #pragma unroll
                for (int r = 0; r < 4; ++r)
                    dst[r * DDIM] = acc[mi][ni][r];
            }
    }
}

// ---------------------------------------------------------------------------
extern "C" void kernel_launch(void* const* d_in, const int* in_sizes, int n_in,
                              void* d_out, int out_size, void* d_ws, size_t ws_size,
                              hipStream_t stream) {
    const float* x  = (const float*)d_in[0];
    const float* Wq = (const float*)d_in[1];
    const float* Wk = (const float*)d_in[2];
    const float* Wv = (const float*)d_in[3];
    const float* Wo = (const float*)d_in[4];
    const float* Ad = (const float*)d_in[5];
    const float* Bd = (const float*)d_in[6];
    const float* Cd = (const float*)d_in[7];

    bf16*  Wt  = (bf16*)d_ws;                      // 448*448*2 = 392 KiB scratch
    float* out = (float*)d_out;

    const int M = in_sizes[0] / DDIM;              // 32768

    prep_wc<<<dim3(7, 7), 256, 0, stream>>>(Wq, Wk, Wv, Wo, Ad, Bd, Cd, Wt);
    gemm_xwc<<<M / 128, 512, 0, stream>>>(x, Wt, out);
}